// Round 3
// baseline (142.547 us; speedup 1.0000x reference)
//
#include <hip/hip_runtime.h>

// ContextGenerator: B=32, D=NOTE_RES=64, T=4096, fp32.
// res[b,t] = sum_{L=low..min(63,up-1)} dm[b,L-1,t] * sum_{w<L} d_L[w]*pm[b,w,t]
// d_L for L in [M,2M), pad=L-M:  d_L = [ x_l[0:2pad], x_{l+1}[pad:M] ].
//
// R2: double-buffered persistent slices. Each block owns 4 consecutive 64-t
// slices; while computing slice s it async-stages slice s+1 (global_load_lds)
// into the other LDS buffer and prefetches its dm rows into a second register
// set -> continuous HBM request flow instead of burst/drain phases.
// 512 blocks = 2/CU (LDS-limited: 65280 B static). pm row 62 lives in a
// register (only 1 FMA uses it) to fit 2 buffers under the 64 KB static limit.

#define TT 4096
#define ROWS 126            // 64 rep rows + 62 pm rows (pm row 62 in a reg)
#define BUFF (ROWS * 64)    // floats per buffer

__device__ __forceinline__ void async_load_f32(const float* g, float* l) {
  __builtin_amdgcn_global_load_lds(
      (const __attribute__((address_space(1))) void*)g,
      (__attribute__((address_space(3))) void*)l, 4, 0, 0);
}

// Stage rep rows 0..63 and pm rows 0..61 for one 64-t slice into buf.
__device__ __forceinline__ void stage(const float* __restrict__ rep,
                                      const float* __restrict__ pm, size_t base,
                                      float* buf, int wid, int lane) {
  for (int r = wid; r < ROWS; r += 4) {  // wave-uniform r
    const float* src = (r < 64) ? rep + base + (size_t)r * TT
                                : pm + base + (size_t)(r - 64) * TT;
    async_load_f32(src + lane, &buf[r * 64]);
  }
}

// Per-role dm prefetch (+ pm row 62 for role2) into registers.
__device__ __forceinline__ void load_dm(const float* __restrict__ dmb,
                                        const float* __restrict__ pmb, int wid,
                                        float* dmr, float& pm62) {
  if (wid == 0) {
#pragma unroll
    for (int i = 0; i < 6; ++i) dmr[i] = dmb[(size_t)(31 + i) * TT];
  } else if (wid == 1) {
#pragma unroll
    for (int i = 0; i < 7; ++i) dmr[i] = dmb[(size_t)(37 + i) * TT];
  } else if (wid == 2) {
#pragma unroll
    for (int i = 0; i < 19; ++i) dmr[i] = dmb[(size_t)(44 + i) * TT];
    pm62 = pmb[(size_t)62 * TT];
  } else {
#pragma unroll
    for (int i = 0; i < 31; ++i) dmr[i] = dmb[(size_t)i * TT];
  }
}

// Waves 0-2: partial of group32 over pad range [P0, P1). dmr[i]=dm row 31+P0+i.
template <int P0, int P1>
__device__ __forceinline__ float role32(const float* __restrict__ lrep,
                                        const float* __restrict__ lpm,
                                        const float* dmr, float pm62, int lane,
                                        int low, int up) {
  float xa[32 - P0];
#pragma unroll
  for (int k = P0; k < 32; ++k)
    xa[k - P0] = 0.5f * (lrep[(2 * k) * 64 + lane] + lrep[(2 * k + 1) * 64 + lane]);
  float q[P1 - 1];
#pragma unroll
  for (int j = 0; j < P1 - 1; ++j)
    q[j] = lrep[(2 * j) * 64 + lane] * lpm[(2 * j) * 64 + lane] +
           lrep[(2 * j + 1) * 64 + lane] * lpm[(2 * j + 1) * 64 + lane];
  float p = 0.f;
#pragma unroll
  for (int j = 0; j < P0; ++j) p += q[j];
  float res = 0.f;
#pragma unroll
  for (int pad = P0; pad < P1; ++pad) {
    const int L = 32 + pad;
    float s = p;  // sum_{w<2*pad} x0[w]*pm[w]
#pragma unroll
    for (int k = pad; k < 32; ++k) {
      const float pv = (k + pad == 62) ? pm62 : lpm[(k + pad) * 64 + lane];
      s = fmaf(xa[k - P0], pv, s);
    }
    if (L >= low && L < up) res = fmaf(dmr[pad - P0], s, res);
    if (pad + 1 < P1) p += q[pad];
  }
  return res;
}

// Wave 3: pyramid levels M=16..1. dmr[i] = dm row i (i in 0..30).
template <int M>
__device__ __forceinline__ void down_lds(const float* __restrict__ lpm, int lane,
                                         float* xa, float* q) {
#pragma unroll
  for (int j = 0; j < M; ++j) {
    const float a = xa[2 * j];
    const float c = xa[2 * j + 1];
    q[j] = a * lpm[(2 * j) * 64 + lane] + c * lpm[(2 * j + 1) * 64 + lane];
    xa[j] = 0.5f * (a + c);
  }
}

template <int M>
__device__ __forceinline__ void acc_lds(const float* __restrict__ lpm,
                                        const float* dmr, int lane,
                                        const float* xa, const float* q, int low,
                                        int up, float& res) {
  float p = 0.f;
#pragma unroll
  for (int pad = 0; pad < M; ++pad) {
    const int L = M + pad;
    float s = p;
#pragma unroll
    for (int k = pad; k < M; ++k) s = fmaf(xa[k], lpm[(k + pad) * 64 + lane], s);
    if (L >= low && L < up) res = fmaf(dmr[M - 1 + pad], s, res);
    p += q[pad];
  }
}

__device__ __forceinline__ float role_tail(const float* __restrict__ lrep,
                                           const float* __restrict__ lpm,
                                           const float* dmr, int lane, int low,
                                           int up) {
  float xa[32];
#pragma unroll
  for (int k = 0; k < 32; ++k)
    xa[k] = 0.5f * (lrep[(2 * k) * 64 + lane] + lrep[(2 * k + 1) * 64 + lane]);
  float q[16];
  float res = 0.f;
  down_lds<16>(lpm, lane, xa, q);
  acc_lds<16>(lpm, dmr, lane, xa, q, low, up, res);
  down_lds<8>(lpm, lane, xa, q);
  acc_lds<8>(lpm, dmr, lane, xa, q, low, up, res);
  down_lds<4>(lpm, lane, xa, q);
  acc_lds<4>(lpm, dmr, lane, xa, q, low, up, res);
  down_lds<2>(lpm, lane, xa, q);
  acc_lds<2>(lpm, dmr, lane, xa, q, low, up, res);
  down_lds<1>(lpm, lane, xa, q);
  acc_lds<1>(lpm, dmr, lane, xa, q, low, up, res);
  return res;
}

__device__ __forceinline__ float compute_role(const float* __restrict__ buf,
                                              const float* dmr, float pm62,
                                              int wid, int lane, int low,
                                              int up) {
  const float* lrep = buf;
  const float* lpm = buf + 64 * 64;
  if (wid == 0) return role32<0, 6>(lrep, lpm, dmr, 0.f, lane, low, up);
  if (wid == 1) return role32<6, 13>(lrep, lpm, dmr, 0.f, lane, low, up);
  if (wid == 2) return role32<13, 32>(lrep, lpm, dmr, pm62, lane, low, up);
  return role_tail(lrep, lpm, dmr, lane, low, up);
}

__global__ __launch_bounds__(256, 2) void ContextGenerator_34875134444049_kernel(
    const float* __restrict__ rep, const float* __restrict__ dm,
    const float* __restrict__ pm, const int* __restrict__ lowp,
    const int* __restrict__ upp, float* __restrict__ out) {
  __shared__ float lds[2 * BUFF + 192];  // 65280 B: buf0 | buf1 | partials(3x64)
  const int wid = threadIdx.x >> 6;
  const int lane = threadIdx.x & 63;
  const int b = blockIdx.x >> 4;          // 512 blocks: 16 per batch
  const int c0 = (blockIdx.x & 15) << 2;  // first of 4 consecutive 64-t chunks
  const size_t bbase = (size_t)b * 64 * TT;
  float* part = lds + 2 * BUFF;

  const int low = lowp[0];
  const int up = upp[0];

  float dmrA[31], dmrB[31];
  float pm62A = 0.f, pm62B = 0.f;

  // Prologue: slice 0 -> buf0 / A.
  {
    const size_t base0 = bbase + ((size_t)(c0 + 0) << 6);
    stage(rep, pm, base0, lds, wid, lane);
    load_dm(dm + base0 + lane, pm + base0 + lane, wid, dmrA, pm62A);
  }

  for (int p = 0; p < 2; ++p) {
    const int s0 = 2 * p;
    // ---- slice s0 (buf0 / A); prefetch s0+1 -> buf1 / B
    __syncthreads();  // drain DMA+dm for slice s0
    {
      const size_t basen = bbase + ((size_t)(c0 + s0 + 1) << 6);
      stage(rep, pm, basen, lds + BUFF, wid, lane);
      load_dm(dm + basen + lane, pm + basen + lane, wid, dmrB, pm62B);
    }
    const float r0 = compute_role(lds, dmrA, pm62A, wid, lane, low, up);
    if (wid < 3) part[wid * 64 + lane] = r0;
    __syncthreads();  // partials visible (also drains s0+1 prefetch)
    if (wid == 3)
      out[(size_t)b * TT + ((size_t)(c0 + s0) << 6) + lane] =
          r0 + part[lane] + part[64 + lane] + part[128 + lane];

    // ---- slice s0+1 (buf1 / B); prefetch s0+2 -> buf0 / A
    __syncthreads();
    if (p == 0) {
      const size_t basen = bbase + ((size_t)(c0 + s0 + 2) << 6);
      stage(rep, pm, basen, lds, wid, lane);
      load_dm(dm + basen + lane, pm + basen + lane, wid, dmrA, pm62A);
    }
    const float r1 = compute_role(lds + BUFF, dmrB, pm62B, wid, lane, low, up);
    if (wid < 3) part[wid * 64 + lane] = r1;
    __syncthreads();
    if (wid == 3)
      out[(size_t)b * TT + ((size_t)(c0 + s0 + 1) << 6) + lane] =
          r1 + part[lane] + part[64 + lane] + part[128 + lane];
  }
}

extern "C" void kernel_launch(void* const* d_in, const int* in_sizes, int n_in,
                              void* d_out, int out_size, void* d_ws,
                              size_t ws_size, hipStream_t stream) {
  const float* rep = (const float*)d_in[0];
  const float* dm = (const float*)d_in[1];
  const float* pm = (const float*)d_in[2];
  const int* lowp = (const int*)d_in[3];
  const int* upp = (const int*)d_in[4];
  float* out = (float*)d_out;

  const int blocks = out_size / 256;  // 131072 / (64 t * 4 slices) = 512
  ContextGenerator_34875134444049_kernel<<<blocks, 256, 0, stream>>>(
      rep, dm, pm, lowp, upp, out);
}

// Round 4
// 123.894 us; speedup vs baseline: 1.1506x; 1.1506x over previous
//
#include <hip/hip_runtime.h>

// ContextGenerator: B=32, D=NOTE_RES=64, T=4096, fp32.
// res[b,t] = sum_{L=low..min(63,up-1)} dm[b,L-1,t] * sum_{w<L} d_L[w]*pm[b,w,t]
// d_L for L in [M,2M), pad=L-M:  d_L = [ x_l[0:2pad], x_{l+1}[pad:M] ].
//
// R3: single-shot blocks (2048, one 64-t slice each), but ALL inputs (rep,
// pm, dm: 192 rows) staged via width-16 global_load_lds (48 insts/block,
// 1 KB each). No per-lane global loads -> no VGPR load chains, no spills
// (R2's 31 MB scratch WRITE_SIZE). LDS 49.9 KB -> 3 resident blocks/CU;
// staging bursts overlap neighbors' compute. Work split across 4 waves by
// uniform role; partials reduced through LDS.

#define TT 4096

__device__ __forceinline__ void async_load16(const float* g, float* l) {
  __builtin_amdgcn_global_load_lds(
      (const __attribute__((address_space(1))) void*)g,
      (__attribute__((address_space(3))) void*)l, 16, 0, 0);
}

// Waves 0-2: partial of group32 over pad range [P0, P1).
// lrep = lds rows 0..63, lpm = rows 64..127, ldm = rows 128..191.
template <int P0, int P1>
__device__ __forceinline__ float role32(const float* __restrict__ lrep,
                                        const float* __restrict__ lpm,
                                        const float* __restrict__ ldm, int lane,
                                        int low, int up) {
  float xa[32 - P0];
#pragma unroll
  for (int k = P0; k < 32; ++k)
    xa[k - P0] = 0.5f * (lrep[(2 * k) * 64 + lane] + lrep[(2 * k + 1) * 64 + lane]);
  float q[P1 - 1];
#pragma unroll
  for (int j = 0; j < P1 - 1; ++j)
    q[j] = lrep[(2 * j) * 64 + lane] * lpm[(2 * j) * 64 + lane] +
           lrep[(2 * j + 1) * 64 + lane] * lpm[(2 * j + 1) * 64 + lane];
  float p = 0.f;
#pragma unroll
  for (int j = 0; j < P0; ++j) p += q[j];
  float res = 0.f;
#pragma unroll
  for (int pad = P0; pad < P1; ++pad) {
    const int L = 32 + pad;
    float s = p;  // sum_{w<2*pad} x0[w]*pm[w]
#pragma unroll
    for (int k = pad; k < 32; ++k)
      s = fmaf(xa[k - P0], lpm[(k + pad) * 64 + lane], s);
    if (L >= low && L < up)
      res = fmaf(ldm[(31 + pad) * 64 + lane], s, res);
    if (pad + 1 < P1) p += q[pad];
  }
  return res;
}

// Wave 3: pyramid levels M=16..1.
template <int M>
__device__ __forceinline__ void down_lds(const float* __restrict__ lpm, int lane,
                                         float* xa, float* q) {
#pragma unroll
  for (int j = 0; j < M; ++j) {
    const float a = xa[2 * j];
    const float c = xa[2 * j + 1];
    q[j] = a * lpm[(2 * j) * 64 + lane] + c * lpm[(2 * j + 1) * 64 + lane];
    xa[j] = 0.5f * (a + c);
  }
}

template <int M>
__device__ __forceinline__ void acc_lds(const float* __restrict__ lpm,
                                        const float* __restrict__ ldm, int lane,
                                        const float* xa, const float* q, int low,
                                        int up, float& res) {
  float p = 0.f;
#pragma unroll
  for (int pad = 0; pad < M; ++pad) {
    const int L = M + pad;
    float s = p;
#pragma unroll
    for (int k = pad; k < M; ++k) s = fmaf(xa[k], lpm[(k + pad) * 64 + lane], s);
    if (L >= low && L < up)
      res = fmaf(ldm[(M - 1 + pad) * 64 + lane], s, res);
    p += q[pad];
  }
}

__device__ __forceinline__ float role_tail(const float* __restrict__ lrep,
                                           const float* __restrict__ lpm,
                                           const float* __restrict__ ldm,
                                           int lane, int low, int up) {
  float xa[32];
#pragma unroll
  for (int k = 0; k < 32; ++k)
    xa[k] = 0.5f * (lrep[(2 * k) * 64 + lane] + lrep[(2 * k + 1) * 64 + lane]);
  float q[16];
  float res = 0.f;
  down_lds<16>(lpm, lane, xa, q);
  acc_lds<16>(lpm, ldm, lane, xa, q, low, up, res);
  down_lds<8>(lpm, lane, xa, q);
  acc_lds<8>(lpm, ldm, lane, xa, q, low, up, res);
  down_lds<4>(lpm, lane, xa, q);
  acc_lds<4>(lpm, ldm, lane, xa, q, low, up, res);
  down_lds<2>(lpm, lane, xa, q);
  acc_lds<2>(lpm, ldm, lane, xa, q, low, up, res);
  down_lds<1>(lpm, lane, xa, q);
  acc_lds<1>(lpm, ldm, lane, xa, q, low, up, res);
  return res;
}

__global__ __launch_bounds__(256, 3) void ContextGenerator_34875134444049_kernel(
    const float* __restrict__ rep, const float* __restrict__ dm,
    const float* __restrict__ pm, const int* __restrict__ lowp,
    const int* __restrict__ upp, float* __restrict__ out) {
  // 192 data rows (64 rep | 64 pm | 64 dm) * 256 B + 3*64 partials = 49.9 KB
  __shared__ float lds[192 * 64 + 192];
  const int wid = threadIdx.x >> 6;
  const int lane = threadIdx.x & 63;
  const int b = blockIdx.x >> 6;          // 2048 blocks: 64 chunks per batch
  const int t0 = (blockIdx.x & 63) << 6;  // 64-t slice
  const size_t base = (size_t)b * 64 * TT + (size_t)t0;

  // Width-16 staging: instruction g stages rows 4g..4g+3 (1 KB). Lane l
  // fetches row 4g + l/16, floats 4*(l%16)..+3; LDS dest = base + 16*l.
  const size_t lv = (size_t)(lane >> 4) * TT + (size_t)((lane & 15) << 2);
  for (int g = wid; g < 48; g += 4) {  // wave-uniform g
    const float* tbase = (g < 16) ? rep + base
                       : (g < 32) ? pm + base - (size_t)64 * TT
                                  : dm + base - (size_t)128 * TT;
    const float* src = tbase + (size_t)(g << 2) * TT + lv;
    async_load16(src, &lds[g * 256]);
  }

  const int low = lowp[0];
  const int up = upp[0];

  __syncthreads();  // drains global_load_lds (vmcnt) + barrier

  const float* lrep = lds;
  const float* lpm = lds + 64 * 64;
  const float* ldm = lds + 128 * 64;
  float* part = lds + 192 * 64;

  float res;
  if (wid == 0)
    res = role32<0, 6>(lrep, lpm, ldm, lane, low, up);
  else if (wid == 1)
    res = role32<6, 13>(lrep, lpm, ldm, lane, low, up);
  else if (wid == 2)
    res = role32<13, 32>(lrep, lpm, ldm, lane, low, up);
  else
    res = role_tail(lrep, lpm, ldm, lane, low, up);

  if (wid < 3) part[wid * 64 + lane] = res;
  __syncthreads();
  if (wid == 3)
    out[(size_t)b * TT + t0 + lane] =
        res + part[lane] + part[64 + lane] + part[128 + lane];
}

extern "C" void kernel_launch(void* const* d_in, const int* in_sizes, int n_in,
                              void* d_out, int out_size, void* d_ws,
                              size_t ws_size, hipStream_t stream) {
  const float* rep = (const float*)d_in[0];
  const float* dm = (const float*)d_in[1];
  const float* pm = (const float*)d_in[2];
  const int* lowp = (const int*)d_in[3];
  const int* upp = (const int*)d_in[4];
  float* out = (float*)d_out;

  const int blocks = out_size / 64;  // 131072 / 64 = 2048
  ContextGenerator_34875134444049_kernel<<<blocks, 256, 0, stream>>>(
      rep, dm, pm, lowp, upp, out);
}